// Round 5
// baseline (334.971 us; speedup 1.0000x reference)
//
#include <hip/hip_runtime.h>

// InputPreprocessor — B=2048, N=32, M=8, D_PAIR=37, H=128.
// features_el_el in the reference is DEAD CODE. Live outputs (both f32):
//   out0 = features_el  [B,N,424]  (ion-summed 2-layer silu MLP || flat feats)
//   out1 = features_ion [B,8,32]
// R5: conflict-free LDS layouts ([tile][chunk][lane][8] => b128 = base+lane*16),
// layer-0 computed transposed (A=W0^T, B=feat^T) so the C->A transform for
// layer 1 is a cross-quad register shuffle (no LDS round-trip, no h0s buffer).
// b0 folded into MFMA via constant-1.0 feature at k=37. LDS 54272 B -> 3 blk/CU.

typedef __attribute__((ext_vector_type(8))) short short8;
typedef __attribute__((ext_vector_type(4))) float f32x4;
typedef __attribute__((ext_vector_type(4))) int   int4v;

#define ITERS     8
#define ROWLEN    424
#define OUT_EL    27787264   // 65536*424

__device__ __forceinline__ unsigned short f2bf(float f){
    unsigned int u = __builtin_bit_cast(unsigned int, f);
    u += 0x7fffu + ((u >> 16) & 1u);     // RNE
    return (unsigned short)(u >> 16);
}
__device__ __forceinline__ float fast_silu(float x){
    return x * __builtin_amdgcn_rcpf(1.0f + __expf(-x));
}

__global__ __launch_bounds__(256, 3)
void el_kernel(const float* __restrict__ r,
               const float* __restrict__ Rion,
               const float* __restrict__ W0,
               const float* __restrict__ b0,
               const float* __restrict__ W1,
               const float* __restrict__ b1,
               float* __restrict__ out)
{
    // All MFMA-read layouts are [tile][chunk][lane64][8 shorts]:
    // a wave's b128 read = base + lane*16 -> conflict-free.
    __shared__ __align__(16) unsigned short W0L[8][2][64][8];   // 16384 B (A: W0^T + b0 row, k-chunk2)
    __shared__ __align__(16) unsigned short W1L[8][4][64][8];   // 32768 B (B: W1)
    __shared__ __align__(16) unsigned short featL[4][4][16][8]; //  4096 B (B: feat^T k=0..31, per wave)
    __shared__ __align__(16) unsigned short featbL[4][16][8];   //  1024 B (k=32..37(=1.0),38,39=0)
    // total 54272 B -> 3 blocks/CU

    const int t    = threadIdx.x;
    const int lane = t & 63;
    const int w    = t >> 6;       // wave 0..3, owns edges frow 16w..16w+15
    const int quad = lane >> 4;
    const int l16  = lane & 15;

    // ---- stage W0L: A-frag for layer 0 (M=channel, K=feature) ----
    // chunk0: k=quad*8+j (0..31) ; chunk1: k=32+quad*8+j, valid only quad0 j<6
    for (int i = t; i < 8*2*64*8; i += 256){
        int j = i & 7, ln = (i >> 3) & 63, ch = (i >> 9) & 1, tc = i >> 10;
        int q = ln >> 4, n = tc*16 + (ln & 15);
        float v = 0.f;
        if (ch == 0)            v = W0[(q*8 + j)*128 + n];
        else if (q == 0){
            if      (j < 5)     v = W0[(32 + j)*128 + n];
            else if (j == 5)    v = b0[n];                 // bias via 1.0-feature
        }
        ((unsigned short*)W0L)[i] = f2bf(v);
    }
    // ---- stage W1L: B-frag for layer 1 (K=channel, N=out-channel) ----
    for (int i = t; i < 8*4*64*8; i += 256){
        int j = i & 7, ln = (i >> 3) & 63, c = (i >> 9) & 3, tc = i >> 11;
        int k = c*32 + (ln >> 4)*8 + j, n = tc*16 + (ln & 15);
        ((unsigned short*)W1L)[i] = f2bf(W1[k*128 + n]);
    }
    // ---- featbL constant slots: j=5 -> 1.0 (bias feature), j=6,7 -> 0 ----
    if (t < 64){
        featbL[t >> 4][t & 15][5] = 0x3F80;
        featbL[t >> 4][t & 15][6] = 0;
        featbL[t >> 4][t & 15][7] = 0;
    }

    float b1v[8];
    #pragma unroll
    for (int tc = 0; tc < 8; ++tc) b1v[tc] = b1[tc*16 + l16];

    // feature-phase mapping: 4 threads per edge; wave-local (frow>>4 == w)
    const int frow  = t >> 2;      // edge 0..63 = ul*8 + m
    const int phase = t & 3;
    const int ul    = frow >> 3;
    const int m     = frow & 7;
    const float Rx = Rion[m*3+0];
    const float Ry = Rion[m*3+1];
    const float Rz = Rion[m*3+2];

    const f32x4 zeroc = {0.f,0.f,0.f,0.f};

    __syncthreads();   // weights staged; loop body is wave-local (no in-loop barriers)

    const int ubase0 = blockIdx.x * (8 * ITERS);

    for (int it = 0; it < ITERS; ++it){
        const int ubase = ubase0 + it * 8;

        // ---------- features: bf16 -> featL (B-layout) + exact f32 -> out ----------
        {
            int gu = ubase + ul;
            float dx = r[gu*3+0] - Rx;
            float dy = r[gu*3+1] - Ry;
            float dz = r[gu*3+2] - Rz;
            float d2 = dx*dx + dy*dy + dz*dz;
            float d  = __builtin_amdgcn_sqrtf(d2);
            float* orow = &out[(size_t)gu*ROWLEN + 128 + m*37];
            for (int f = phase; f < 37; f += 4){
                float val;
                if (f < 32){
                    float q  = (float)f * (1.0f/31.0f);
                    float mu = q*q*5.0f;
                    float is = 7.0f * __builtin_amdgcn_rcpf(1.0f + 5.0f*q);
                    float uu = (d - mu) * is;
                    val = d2 * __expf(-d - uu*uu);
                } else if (f == 32) val = d;
                else if (f == 33)   val = 1.0f / (d + 0.01f);
                else if (f == 34)   val = dx;
                else if (f == 35)   val = dy;
                else                val = dz;
                orow[f] = val;
                unsigned short ub = f2bf(val);
                if (f < 32) featL[w][f >> 3][frow & 15][f & 7] = ub;
                else        featbL[w][frow & 15][f - 32]       = ub;
            }
        }

        // ---------- layer 0 (transposed): D0 = W0^T @ feat^T ----------
        // B-frags depend only on (chunk, lane), read once:
        short8 bf0 = *(const short8*)&featL[w][quad][l16][0];   // k = quad*8+j
        short8 bf1 = *(const short8*)&featbL[w][l16][0];        // k = 32+..., A=0 where invalid
        f32x4 acc0[8];
        #pragma unroll
        for (int tc = 0; tc < 8; ++tc){
            short8 a0 = *(const short8*)&W0L[tc][0][lane][0];
            short8 a1 = *(const short8*)&W0L[tc][1][lane][0];
            f32x4 acc = __builtin_amdgcn_mfma_f32_16x16x32_bf16(a0, bf0, zeroc, 0, 0, 0);
            acc0[tc]  = __builtin_amdgcn_mfma_f32_16x16x32_bf16(a1, bf1, acc,   0, 0, 0);
        }
        // C-layout: lane holds channels n = tc*16 + quad*4 + rr, edge col = l16.
        // silu + pack rr-pairs: P[tc][p] = channels (.., ..+1) bf16x2
        unsigned int P[8][2];
        #pragma unroll
        for (int tc = 0; tc < 8; ++tc){
            #pragma unroll
            for (int p = 0; p < 2; ++p){
                unsigned int lo = f2bf(fast_silu(acc0[tc][2*p]));
                unsigned int hi = f2bf(fast_silu(acc0[tc][2*p+1]));
                P[tc][p] = lo | (hi << 16);
            }
        }

        // ---------- layer 1: D1[e][n] = h0[e][k] W1[k][n] ----------
        // A-frag: lane needs edge=l16, k=c*32+quad*8+j. Source: same l16,
        // quad_s=(quad&1)*2+(jp>>1), reg P[c*2+(quad>>1)][jp&1] -> cross-quad shfl.
        f32x4 acc1[8];
        #pragma unroll
        for (int i = 0; i < 8; ++i) acc1[i] = zeroc;
        const int srcA = ((quad & 1) * 2) * 16 + l16;
        const bool hiHalf = (quad >> 1) != 0;
        #pragma unroll
        for (int c = 0; c < 4; ++c){
            int4v qv;
            #pragma unroll
            for (int jp = 0; jp < 4; ++jp){
                int src = srcA + ((jp >> 1) << 4);
                int t0 = __shfl((int)P[c*2 + 0][jp & 1], src, 64);
                int t1 = __shfl((int)P[c*2 + 1][jp & 1], src, 64);
                qv[jp] = hiHalf ? t1 : t0;
            }
            short8 af = __builtin_bit_cast(short8, qv);
            #pragma unroll
            for (int tc = 0; tc < 8; ++tc){
                short8 bw = *(const short8*)&W1L[tc][c][lane][0];
                acc1[tc] = __builtin_amdgcn_mfma_f32_16x16x32_bf16(af, bw, acc1[tc], 0, 0, 0);
            }
        }
        // bias + silu + ion-sum over rows (e = quad*4+rr), store one_el f32
        #pragma unroll
        for (int tc = 0; tc < 8; ++tc){
            float v = 0.f;
            #pragma unroll
            for (int rr = 0; rr < 4; ++rr) v += fast_silu(acc1[tc][rr] + b1v[tc]);
            v += __shfl_xor(v, 16, 64);   // quad0+1 -> unit 2w; quad2+3 -> unit 2w+1
            if ((quad & 1) == 0){
                size_t gu = (size_t)(ubase + 2*w + (quad >> 1));
                out[gu*ROWLEN + tc*16 + l16] = v;
            }
        }
    }
}

__global__ __launch_bounds__(256)
void ion_kernel(const float* __restrict__ Z,
                const float* __restrict__ Wion,
                const float* __restrict__ bion,
                float* __restrict__ out1)
{
    int gid = blockIdx.x*256 + threadIdx.x;   // 131072 threads, 4 elems each
    int e0 = gid*4;
    float4 v;
    float* pv = &v.x;
    #pragma unroll
    for (int qi = 0; qi < 4; ++qi){
        int e = e0 + qi;
        int j = e & 31, mm = (e >> 5) & 7;
        pv[qi] = fast_silu(Z[mm] * Wion[j] + bion[j]);
    }
    *(float4*)&out1[e0] = v;
}

extern "C" void kernel_launch(void* const* d_in, const int* in_sizes, int n_in,
                              void* d_out, int out_size, void* d_ws, size_t ws_size,
                              hipStream_t stream)
{
    const float* r    = (const float*)d_in[0];
    const float* Rion = (const float*)d_in[1];
    const float* Z    = (const float*)d_in[2];
    const float* W0   = (const float*)d_in[3];
    const float* b0   = (const float*)d_in[4];
    const float* W1   = (const float*)d_in[5];
    const float* b1   = (const float*)d_in[6];
    const float* Wion = (const float*)d_in[7];
    const float* bion = (const float*)d_in[8];
    float* out = (float*)d_out;

    el_kernel<<<dim3(1024), dim3(256), 0, stream>>>(r, Rion, W0, b0, W1, b1, out);
    ion_kernel<<<dim3(512), dim3(256), 0, stream>>>(Z, Wion, bion, out + OUT_EL);
}

// Round 6
// 249.565 us; speedup vs baseline: 1.3422x; 1.3422x over previous
//
#include <hip/hip_runtime.h>

// InputPreprocessor — B=2048, N=32, M=8, D_PAIR=37, H=128.
// features_el_el in the reference is DEAD CODE. Live outputs (both f32):
//   out0 = features_el  [B,N,424]  (ion-summed 2-layer silu MLP || flat feats)
//   out1 = features_ion [B,8,32]
// R6: R5's conflict-free LDS layouts kept; spill fixed by (a) launch_bounds
// back to (256,2) (R5's (256,3) caused 440 MB scratch fetch), (b) consuming
// the layer-0 outputs P via shuffles IMMEDIATELY (af[4] built before acc1
// loop, so P/acc0 die early — shorter live ranges, no spill).

typedef __attribute__((ext_vector_type(8))) short short8;
typedef __attribute__((ext_vector_type(4))) float f32x4;
typedef __attribute__((ext_vector_type(4))) int   int4v;

#define ITERS     8
#define ROWLEN    424
#define OUT_EL    27787264   // 65536*424

__device__ __forceinline__ unsigned short f2bf(float f){
    unsigned int u = __builtin_bit_cast(unsigned int, f);
    u += 0x7fffu + ((u >> 16) & 1u);     // RNE
    return (unsigned short)(u >> 16);
}
__device__ __forceinline__ float fast_silu(float x){
    return x * __builtin_amdgcn_rcpf(1.0f + __expf(-x));
}

__global__ __launch_bounds__(256, 2)
void el_kernel(const float* __restrict__ r,
               const float* __restrict__ Rion,
               const float* __restrict__ W0,
               const float* __restrict__ b0,
               const float* __restrict__ W1,
               const float* __restrict__ b1,
               float* __restrict__ out)
{
    // All MFMA-read layouts are [tile][chunk][lane64][8 shorts]:
    // a wave's b128 read = base + lane*16 -> conflict-free.
    __shared__ __align__(16) unsigned short W0L[8][2][64][8];   // 16384 B (A: W0^T + b0 row)
    __shared__ __align__(16) unsigned short W1L[8][4][64][8];   // 32768 B (B: W1)
    __shared__ __align__(16) unsigned short featL[4][4][16][8]; //  4096 B (B: feat^T k=0..31)
    __shared__ __align__(16) unsigned short featbL[4][16][8];   //  1024 B (k=32..36, 37=1.0, 38/39=0)
    // total 54272 B

    const int t    = threadIdx.x;
    const int lane = t & 63;
    const int w    = t >> 6;       // wave 0..3, owns edges frow 16w..16w+15
    const int quad = lane >> 4;
    const int l16  = lane & 15;

    // ---- stage W0L: A-frag for layer 0 (M=channel, K=feature) ----
    for (int i = t; i < 8*2*64*8; i += 256){
        int j = i & 7, ln = (i >> 3) & 63, ch = (i >> 9) & 1, tc = i >> 10;
        int q = ln >> 4, n = tc*16 + (ln & 15);
        float v = 0.f;
        if (ch == 0)            v = W0[(q*8 + j)*128 + n];
        else if (q == 0){
            if      (j < 5)     v = W0[(32 + j)*128 + n];
            else if (j == 5)    v = b0[n];                 // bias via 1.0-feature
        }
        ((unsigned short*)W0L)[i] = f2bf(v);
    }
    // ---- stage W1L: B-frag for layer 1 (K=channel, N=out-channel) ----
    for (int i = t; i < 8*4*64*8; i += 256){
        int j = i & 7, ln = (i >> 3) & 63, c = (i >> 9) & 3, tc = i >> 11;
        int k = c*32 + (ln >> 4)*8 + j, n = tc*16 + (ln & 15);
        ((unsigned short*)W1L)[i] = f2bf(W1[k*128 + n]);
    }
    // ---- featbL constant slots: j=5 -> 1.0 (bias feature), j=6,7 -> 0 ----
    if (t < 64){
        featbL[t >> 4][t & 15][5] = 0x3F80;
        featbL[t >> 4][t & 15][6] = 0;
        featbL[t >> 4][t & 15][7] = 0;
    }

    // feature-phase mapping: 4 threads per edge; wave-local (frow>>4 == w)
    const int frow  = t >> 2;      // edge 0..63 = ul*8 + m
    const int phase = t & 3;
    const int ul    = frow >> 3;
    const int m     = frow & 7;
    const float Rx = Rion[m*3+0];
    const float Ry = Rion[m*3+1];
    const float Rz = Rion[m*3+2];

    const f32x4 zeroc = {0.f,0.f,0.f,0.f};

    __syncthreads();   // weights staged; loop body is wave-local (no in-loop barriers)

    const int ubase0 = blockIdx.x * (8 * ITERS);

    for (int it = 0; it < ITERS; ++it){
        const int ubase = ubase0 + it * 8;

        // ---------- features: bf16 -> featL (B-layout) + exact f32 -> out ----------
        {
            int gu = ubase + ul;
            float dx = r[gu*3+0] - Rx;
            float dy = r[gu*3+1] - Ry;
            float dz = r[gu*3+2] - Rz;
            float d2 = dx*dx + dy*dy + dz*dz;
            float d  = __builtin_amdgcn_sqrtf(d2);
            float* orow = &out[(size_t)gu*ROWLEN + 128 + m*37];
            for (int f = phase; f < 37; f += 4){
                float val;
                if (f < 32){
                    float q  = (float)f * (1.0f/31.0f);
                    float mu = q*q*5.0f;
                    float is = 7.0f * __builtin_amdgcn_rcpf(1.0f + 5.0f*q);
                    float uu = (d - mu) * is;
                    val = d2 * __expf(-d - uu*uu);
                } else if (f == 32) val = d;
                else if (f == 33)   val = 1.0f / (d + 0.01f);
                else if (f == 34)   val = dx;
                else if (f == 35)   val = dy;
                else                val = dz;
                orow[f] = val;
                unsigned short ub = f2bf(val);
                if (f < 32) featL[w][f >> 3][frow & 15][f & 7] = ub;
                else        featbL[w][frow & 15][f - 32]       = ub;
            }
        }

        // ---------- layer 0 (transposed): D0 = W0^T @ feat^T ----------
        short8 bf0 = *(const short8*)&featL[w][quad][l16][0];   // k = quad*8+j
        short8 bf1 = *(const short8*)&featbL[w][l16][0];        // k = 32+...
        // A-frags for layer 1, built incrementally as P values are produced.
        int4v af[4];
        {
            const int srcA   = ((quad & 1) * 2) * 16 + l16;
            const bool hiHalf = (quad >> 1) != 0;
            #pragma unroll
            for (int tc = 0; tc < 8; ++tc){
                short8 a0 = *(const short8*)&W0L[tc][0][lane][0];
                short8 a1 = *(const short8*)&W0L[tc][1][lane][0];
                f32x4 acc = __builtin_amdgcn_mfma_f32_16x16x32_bf16(a0, bf0, zeroc, 0, 0, 0);
                acc       = __builtin_amdgcn_mfma_f32_16x16x32_bf16(a1, bf1, acc,   0, 0, 0);
                // C-layout: lane holds channels n = tc*16 + quad*4 + rr, edge = l16.
                unsigned int P0 = (unsigned int)f2bf(fast_silu(acc[0])) |
                                  ((unsigned int)f2bf(fast_silu(acc[1])) << 16);
                unsigned int P1 = (unsigned int)f2bf(fast_silu(acc[2])) |
                                  ((unsigned int)f2bf(fast_silu(acc[3])) << 16);
                // consume immediately: cross-quad shuffle into af[tc>>1]
                int c  = tc >> 1;               // which A-frag (k-chunk of layer 1)
                int half = tc & 1;              // source P bank (quad>>1 selector)
                #pragma unroll
                for (int jp = 0; jp < 4; ++jp){
                    int src = srcA + ((jp >> 1) << 4);
                    int tv0 = __shfl((int)P0, src, 64);
                    int tv1 = __shfl((int)P1, src, 64);
                    int tv  = (jp & 1) ? tv1 : tv0;
                    if (half == (hiHalf ? 1 : 0)) af[c][jp] = tv;
                }
            }
        }

        // ---------- layer 1: D1[e][n] = h0[e][k] W1[k][n] ----------
        f32x4 acc1[8];
        #pragma unroll
        for (int i = 0; i < 8; ++i) acc1[i] = zeroc;
        #pragma unroll
        for (int c = 0; c < 4; ++c){
            short8 afk = __builtin_bit_cast(short8, af[c]);
            #pragma unroll
            for (int tc = 0; tc < 8; ++tc){
                short8 bw = *(const short8*)&W1L[tc][c][lane][0];
                acc1[tc] = __builtin_amdgcn_mfma_f32_16x16x32_bf16(afk, bw, acc1[tc], 0, 0, 0);
            }
        }
        // bias + silu + ion-sum over rows (e col block), store one_el f32
        #pragma unroll
        for (int tc = 0; tc < 8; ++tc){
            float v = 0.f;
            float bias = b1[tc*16 + l16];
            #pragma unroll
            for (int rr = 0; rr < 4; ++rr) v += fast_silu(acc1[tc][rr] + bias);
            v += __shfl_xor(v, 16, 64);   // quad0+1 -> unit 2w; quad2+3 -> unit 2w+1
            if ((quad & 1) == 0){
                size_t gu = (size_t)(ubase + 2*w + (quad >> 1));
                out[gu*ROWLEN + tc*16 + l16] = v;
            }
        }
    }
}

__global__ __launch_bounds__(256)
void ion_kernel(const float* __restrict__ Z,
                const float* __restrict__ Wion,
                const float* __restrict__ bion,
                float* __restrict__ out1)
{
    int gid = blockIdx.x*256 + threadIdx.x;   // 131072 threads, 4 elems each
    int e0 = gid*4;
    float4 v;
    float* pv = &v.x;
    #pragma unroll
    for (int qi = 0; qi < 4; ++qi){
        int e = e0 + qi;
        int j = e & 31, mm = (e >> 5) & 7;
        pv[qi] = fast_silu(Z[mm] * Wion[j] + bion[j]);
    }
    *(float4*)&out1[e0] = v;
}

extern "C" void kernel_launch(void* const* d_in, const int* in_sizes, int n_in,
                              void* d_out, int out_size, void* d_ws, size_t ws_size,
                              hipStream_t stream)
{
    const float* r    = (const float*)d_in[0];
    const float* Rion = (const float*)d_in[1];
    const float* Z    = (const float*)d_in[2];
    const float* W0   = (const float*)d_in[3];
    const float* b0   = (const float*)d_in[4];
    const float* W1   = (const float*)d_in[5];
    const float* b1   = (const float*)d_in[6];
    const float* Wion = (const float*)d_in[7];
    const float* bion = (const float*)d_in[8];
    float* out = (float*)d_out;

    el_kernel<<<dim3(1024), dim3(256), 0, stream>>>(r, Rion, W0, b0, W1, b1, out);
    ion_kernel<<<dim3(512), dim3(256), 0, stream>>>(Z, Wion, bion, out + OUT_EL);
}

// Round 7
// 236.609 us; speedup vs baseline: 1.4157x; 1.0548x over previous
//
#include <hip/hip_runtime.h>

// InputPreprocessor — B=2048, N=32, M=8, D_PAIR=37, H=128.
// features_el_el in the reference is DEAD CODE. Live outputs (both f32):
//   out0 = features_el  [B,N,424]  (ion-summed 2-layer silu MLP || flat feats)
//   out1 = features_ion [B,8,32]
// R7: same per-wave algorithm as R6 (conflict-free LDS, shuffle C->A
// transform, b0 folded in via 1.0-feature), but block=512 (8 waves) sharing
// ONE weight copy in LDS (59392 B) -> 2 blocks/CU co-resident = 16 waves/CU
// (4/SIMD), doubling latency hiding. R6 measured 2 blocks of 256 (21% occ).

typedef __attribute__((ext_vector_type(8))) short short8;
typedef __attribute__((ext_vector_type(4))) float f32x4;
typedef __attribute__((ext_vector_type(4))) int   int4v;

#define ITERS     8
#define UNITS_IT  16          // units per block-iteration (128 edges)
#define ROWLEN    424
#define OUT_EL    27787264    // 65536*424

__device__ __forceinline__ unsigned short f2bf(float f){
    unsigned int u = __builtin_bit_cast(unsigned int, f);
    u += 0x7fffu + ((u >> 16) & 1u);     // RNE
    return (unsigned short)(u >> 16);
}
__device__ __forceinline__ float fast_silu(float x){
    return x * __builtin_amdgcn_rcpf(1.0f + __expf(-x));
}

__global__ __launch_bounds__(512, 2)
void el_kernel(const float* __restrict__ r,
               const float* __restrict__ Rion,
               const float* __restrict__ W0,
               const float* __restrict__ b0,
               const float* __restrict__ W1,
               const float* __restrict__ b1,
               float* __restrict__ out)
{
    // MFMA-read layouts are [tile][chunk][lane64][8 shorts]: b128 = base+lane*16.
    __shared__ __align__(16) unsigned short W0L[8][2][64][8];   // 16384 B
    __shared__ __align__(16) unsigned short W1L[8][4][64][8];   // 32768 B
    __shared__ __align__(16) unsigned short featL[8][4][16][8]; //  8192 B (per-wave feat^T k=0..31)
    __shared__ __align__(16) unsigned short featbL[8][16][8];   //  2048 B (k=32..36, 37=1.0, 38/39=0)
    // total 59392 B -> 2 blocks (1024 thr) / CU

    const int t    = threadIdx.x;
    const int lane = t & 63;
    const int w    = t >> 6;       // wave 0..7, owns edges frow 16w..16w+15 (units 2w,2w+1)
    const int quad = lane >> 4;
    const int l16  = lane & 15;

    // ---- stage W0L: A-frag for layer 0 (M=channel, K=feature) ----
    for (int i = t; i < 8*2*64*8; i += 512){
        int j = i & 7, ln = (i >> 3) & 63, ch = (i >> 9) & 1, tc = i >> 10;
        int q = ln >> 4, n = tc*16 + (ln & 15);
        float v = 0.f;
        if (ch == 0)            v = W0[(q*8 + j)*128 + n];
        else if (q == 0){
            if      (j < 5)     v = W0[(32 + j)*128 + n];
            else if (j == 5)    v = b0[n];                 // bias via 1.0-feature
        }
        ((unsigned short*)W0L)[i] = f2bf(v);
    }
    // ---- stage W1L: B-frag for layer 1 (K=channel, N=out-channel) ----
    for (int i = t; i < 8*4*64*8; i += 512){
        int j = i & 7, ln = (i >> 3) & 63, c = (i >> 9) & 3, tc = i >> 11;
        int k = c*32 + (ln >> 4)*8 + j, n = tc*16 + (ln & 15);
        ((unsigned short*)W1L)[i] = f2bf(W1[k*128 + n]);
    }
    // ---- featbL constant slots: j=5 -> 1.0 (bias feature), j=6,7 -> 0 ----
    if (t < 128){
        featbL[t >> 4][t & 15][5] = 0x3F80;
        featbL[t >> 4][t & 15][6] = 0;
        featbL[t >> 4][t & 15][7] = 0;
    }

    // feature-phase mapping: 4 threads per edge; wave-local (frow>>4 == w)
    const int frow  = t >> 2;      // edge 0..127 = ul*8 + m
    const int phase = t & 3;
    const int ul    = frow >> 3;   // block-local unit 0..15
    const int m     = frow & 7;
    const float Rx = Rion[m*3+0];
    const float Ry = Rion[m*3+1];
    const float Rz = Rion[m*3+2];

    const f32x4 zeroc = {0.f,0.f,0.f,0.f};

    __syncthreads();   // weights staged; loop body is wave-local (no in-loop barriers)

    const int ubase0 = blockIdx.x * (UNITS_IT * ITERS);

    for (int it = 0; it < ITERS; ++it){
        const int ubase = ubase0 + it * UNITS_IT;

        // ---------- features: bf16 -> featL (B-layout) + exact f32 -> out ----------
        {
            int gu = ubase + ul;
            float dx = r[gu*3+0] - Rx;
            float dy = r[gu*3+1] - Ry;
            float dz = r[gu*3+2] - Rz;
            float d2 = dx*dx + dy*dy + dz*dz;
            float d  = __builtin_amdgcn_sqrtf(d2);
            float* orow = &out[(size_t)gu*ROWLEN + 128 + m*37];
            for (int f = phase; f < 37; f += 4){
                float val;
                if (f < 32){
                    float q  = (float)f * (1.0f/31.0f);
                    float mu = q*q*5.0f;
                    float is = 7.0f * __builtin_amdgcn_rcpf(1.0f + 5.0f*q);
                    float uu = (d - mu) * is;
                    val = d2 * __expf(-d - uu*uu);
                } else if (f == 32) val = d;
                else if (f == 33)   val = 1.0f / (d + 0.01f);
                else if (f == 34)   val = dx;
                else if (f == 35)   val = dy;
                else                val = dz;
                orow[f] = val;
                unsigned short ub = f2bf(val);
                if (f < 32) featL[w][f >> 3][frow & 15][f & 7] = ub;
                else        featbL[w][frow & 15][f - 32]       = ub;
            }
        }

        // ---------- layer 0 (transposed): D0 = W0^T @ feat^T ----------
        short8 bf0 = *(const short8*)&featL[w][quad][l16][0];   // k = quad*8+j
        short8 bf1 = *(const short8*)&featbL[w][l16][0];        // k = 32+...
        // A-frags for layer 1, built incrementally as P values are produced.
        int4v af[4];
        {
            const int srcA   = ((quad & 1) * 2) * 16 + l16;
            const bool hiHalf = (quad >> 1) != 0;
            #pragma unroll
            for (int tc = 0; tc < 8; ++tc){
                short8 a0 = *(const short8*)&W0L[tc][0][lane][0];
                short8 a1 = *(const short8*)&W0L[tc][1][lane][0];
                f32x4 acc = __builtin_amdgcn_mfma_f32_16x16x32_bf16(a0, bf0, zeroc, 0, 0, 0);
                acc       = __builtin_amdgcn_mfma_f32_16x16x32_bf16(a1, bf1, acc,   0, 0, 0);
                // C-layout: lane holds channels n = tc*16 + quad*4 + rr, edge = l16.
                unsigned int P0 = (unsigned int)f2bf(fast_silu(acc[0])) |
                                  ((unsigned int)f2bf(fast_silu(acc[1])) << 16);
                unsigned int P1 = (unsigned int)f2bf(fast_silu(acc[2])) |
                                  ((unsigned int)f2bf(fast_silu(acc[3])) << 16);
                // consume immediately: cross-quad shuffle into af[tc>>1]
                int c    = tc >> 1;             // which A-frag (k-chunk of layer 1)
                int half = tc & 1;              // source P bank (quad>>1 selector)
                #pragma unroll
                for (int jp = 0; jp < 4; ++jp){
                    int src = srcA + ((jp >> 1) << 4);
                    int tv0 = __shfl((int)P0, src, 64);
                    int tv1 = __shfl((int)P1, src, 64);
                    int tv  = (jp & 1) ? tv1 : tv0;
                    if (half == (hiHalf ? 1 : 0)) af[c][jp] = tv;
                }
            }
        }

        // ---------- layer 1: D1[e][n] = h0[e][k] W1[k][n] ----------
        f32x4 acc1[8];
        #pragma unroll
        for (int i = 0; i < 8; ++i) acc1[i] = zeroc;
        #pragma unroll
        for (int c = 0; c < 4; ++c){
            short8 afk = __builtin_bit_cast(short8, af[c]);
            #pragma unroll
            for (int tc = 0; tc < 8; ++tc){
                short8 bw = *(const short8*)&W1L[tc][c][lane][0];
                acc1[tc] = __builtin_amdgcn_mfma_f32_16x16x32_bf16(afk, bw, acc1[tc], 0, 0, 0);
            }
        }
        // bias + silu + ion-sum over rows, store one_el f32
        #pragma unroll
        for (int tc = 0; tc < 8; ++tc){
            float v = 0.f;
            float bias = b1[tc*16 + l16];
            #pragma unroll
            for (int rr = 0; rr < 4; ++rr) v += fast_silu(acc1[tc][rr] + bias);
            v += __shfl_xor(v, 16, 64);   // quad0+1 -> unit 2w; quad2+3 -> unit 2w+1
            if ((quad & 1) == 0){
                size_t gu = (size_t)(ubase + 2*w + (quad >> 1));
                out[gu*ROWLEN + tc*16 + l16] = v;
            }
        }
    }
}

__global__ __launch_bounds__(256)
void ion_kernel(const float* __restrict__ Z,
                const float* __restrict__ Wion,
                const float* __restrict__ bion,
                float* __restrict__ out1)
{
    int gid = blockIdx.x*256 + threadIdx.x;   // 131072 threads, 4 elems each
    int e0 = gid*4;
    float4 v;
    float* pv = &v.x;
    #pragma unroll
    for (int qi = 0; qi < 4; ++qi){
        int e = e0 + qi;
        int j = e & 31, mm = (e >> 5) & 7;
        pv[qi] = fast_silu(Z[mm] * Wion[j] + bion[j]);
    }
    *(float4*)&out1[e0] = v;
}

extern "C" void kernel_launch(void* const* d_in, const int* in_sizes, int n_in,
                              void* d_out, int out_size, void* d_ws, size_t ws_size,
                              hipStream_t stream)
{
    const float* r    = (const float*)d_in[0];
    const float* Rion = (const float*)d_in[1];
    const float* Z    = (const float*)d_in[2];
    const float* W0   = (const float*)d_in[3];
    const float* b0   = (const float*)d_in[4];
    const float* W1   = (const float*)d_in[5];
    const float* b1   = (const float*)d_in[6];
    const float* Wion = (const float*)d_in[7];
    const float* bion = (const float*)d_in[8];
    float* out = (float*)d_out;

    el_kernel<<<dim3(512), dim3(512), 0, stream>>>(r, Rion, W0, b0, W1, b1, out);
    ion_kernel<<<dim3(512), dim3(256), 0, stream>>>(Z, Wion, bion, out + OUT_EL);
}